// Round 1
// baseline (270.219 us; speedup 1.0000x reference)
//
#include <hip/hip_runtime.h>
#include <math.h>

#define EPS_Q 1e-8f

struct F3 { float x, y, z; };
struct Q4 { F3 v; float w; };

__device__ __forceinline__ F3 add3(F3 a, F3 b){ return {a.x+b.x, a.y+b.y, a.z+b.z}; }
__device__ __forceinline__ F3 sub3(F3 a, F3 b){ return {a.x-b.x, a.y-b.y, a.z-b.z}; }
__device__ __forceinline__ F3 scal3(float s, F3 a){ return {s*a.x, s*a.y, s*a.z}; }
__device__ __forceinline__ float dot3(F3 a, F3 b){ return a.x*b.x + a.y*b.y + a.z*b.z; }
__device__ __forceinline__ F3 cross3(F3 a, F3 b){
    return { a.y*b.z - a.z*b.y, a.z*b.x - a.x*b.z, a.x*b.y - a.y*b.x };
}

__device__ __forceinline__ Q4 qmul(Q4 q, Q4 r){
    Q4 o;
    o.w = q.w*r.w - dot3(q.v, r.v);
    o.v = add3(add3(scal3(q.w, r.v), scal3(r.w, q.v)), cross3(q.v, r.v));
    return o;
}
__device__ __forceinline__ Q4 qconj(Q4 q){ return { {-q.v.x, -q.v.y, -q.v.z}, q.w }; }
__device__ __forceinline__ F3 qrot(Q4 q, F3 v){
    F3 t = scal3(2.0f, cross3(q.v, v));
    return add3(add3(v, scal3(q.w, t)), cross3(q.v, t));
}
// matches reference so3_log branch semantics exactly
__device__ __forceinline__ F3 so3_log(Q4 q){
    float n = sqrtf(dot3(q.v, q.v));
    float theta = 2.0f * atan2f(n, q.w);
    float k;
    if (n > EPS_Q) k = theta / n;
    else           k = 2.0f / ((fabsf(q.w) > EPS_Q) ? q.w : 1.0f);
    return scal3(k, q.v);
}

// ---------------- edge residuals: pgerr = se3_log(te, qe) ----------------
__global__ void edge_kernel(const int*   __restrict__ edges,
                            const float* __restrict__ nodes,
                            const float* __restrict__ poses,
                            float*       __restrict__ out,
                            int E)
{
    int e = blockIdx.x * blockDim.x + threadIdx.x;
    if (e >= E) return;

    int i = edges[2*(size_t)e];
    int j = edges[2*(size_t)e + 1];
    const float* n1 = nodes + 7*(size_t)i;
    const float* n2 = nodes + 7*(size_t)j;
    const float* p  = poses + 7*(size_t)e;

    F3 t1 = {n1[0], n1[1], n1[2]};  Q4 q1 = {{n1[3], n1[4], n1[5]}, n1[6]};
    F3 t2 = {n2[0], n2[1], n2[2]};  Q4 q2 = {{n2[3], n2[4], n2[5]}, n2[6]};
    F3 tp = {p[0],  p[1],  p[2]};   Q4 qp = {{p[3],  p[4],  p[5]},  p[6]};

    Q4 qi1 = qconj(q1);
    F3 ti1 = scal3(-1.0f, qrot(qi1, t1));
    Q4 qa  = qmul(qi1, q2);
    F3 ta  = add3(ti1, qrot(qi1, t2));

    Q4 qip = qconj(qp);
    F3 tip = scal3(-1.0f, qrot(qip, tp));
    Q4 qe  = qmul(qip, qa);
    F3 te  = add3(tip, qrot(qip, ta));

    // se3_log(te, qe)
    F3 phi = so3_log(qe);
    float theta2 = dot3(phi, phi);
    float theta  = sqrtf(theta2);
    float coef;
    if (theta < 1e-4f) {
        coef = 1.0f / 12.0f;
    } else {
        coef = 1.0f / theta2 - (1.0f + cosf(theta)) / (2.0f * theta * sinf(theta));
    }
    F3 pxt = cross3(phi, te);
    F3 tau = add3(sub3(te, scal3(0.5f, pxt)), scal3(coef, cross3(phi, pxt)));

    float* o = out + 6*(size_t)e;   // L1 = 1.0
    o[0] = tau.x; o[1] = tau.y; o[2] = tau.z;
    o[3] = phi.x; o[4] = phi.y; o[5] = phi.z;
}

// ---------------- node-adjacency residuals ----------------
__global__ void node_kernel(const float* __restrict__ nodes,
                            const float* __restrict__ vels,
                            const float* __restrict__ imu_drots,
                            const float* __restrict__ imu_dtrans,
                            const float* __restrict__ imu_dvels,
                            const float* __restrict__ dts,
                            float*       __restrict__ out,
                            int M,
                            size_t off_adjvel, size_t off_imurot, size_t off_transvel)
{
    int m = blockIdx.x * blockDim.x + threadIdx.x;
    if (m >= M) return;

    const float* n0 = nodes + 7*(size_t)m;
    const float* n1 = nodes + 7*(size_t)(m+1);
    F3 t0 = {n0[0], n0[1], n0[2]};  Q4 q0 = {{n0[3], n0[4], n0[5]}, n0[6]};
    F3 t1 = {n1[0], n1[1], n1[2]};  Q4 q1 = {{n1[3], n1[4], n1[5]}, n1[6]};

    F3 v0 = {vels[3*(size_t)m],     vels[3*(size_t)m + 1], vels[3*(size_t)m + 2]};
    F3 v1 = {vels[3*(size_t)m + 3], vels[3*(size_t)m + 4], vels[3*(size_t)m + 5]};

    // adjvelerr = imu_dvels - (vels[1:] - vels[:-1]);  L2 = 0.1
    F3 dvm = {imu_dvels[3*(size_t)m], imu_dvels[3*(size_t)m + 1], imu_dvels[3*(size_t)m + 2]};
    F3 adjv = sub3(dvm, sub3(v1, v0));
    out[off_adjvel + 3*(size_t)m    ] = 0.1f * adjv.x;
    out[off_adjvel + 3*(size_t)m + 1] = 0.1f * adjv.y;
    out[off_adjvel + 3*(size_t)m + 2] = 0.1f * adjv.z;

    // imuroterr = so3_log( conj(imu_drots) * (conj(q0) * q1) );  L3 = 1.0
    Q4 dr = {{imu_drots[4*(size_t)m], imu_drots[4*(size_t)m + 1], imu_drots[4*(size_t)m + 2]},
              imu_drots[4*(size_t)m + 3]};
    Q4 qre = qmul(qconj(dr), qmul(qconj(q0), q1));
    F3 rot = so3_log(qre);
    out[off_imurot + 3*(size_t)m    ] = rot.x;
    out[off_imurot + 3*(size_t)m + 1] = rot.y;
    out[off_imurot + 3*(size_t)m + 2] = rot.z;

    // transvelerr = t1 - t0 - (v0 * dt + imu_dtrans);  L4 = 0.1
    float dt = dts[m];
    F3 dtr = {imu_dtrans[3*(size_t)m], imu_dtrans[3*(size_t)m + 1], imu_dtrans[3*(size_t)m + 2]};
    F3 tv = sub3(sub3(t1, t0), add3(scal3(dt, v0), dtr));
    out[off_transvel + 3*(size_t)m    ] = 0.1f * tv.x;
    out[off_transvel + 3*(size_t)m + 1] = 0.1f * tv.y;
    out[off_transvel + 3*(size_t)m + 2] = 0.1f * tv.z;
}

extern "C" void kernel_launch(void* const* d_in, const int* in_sizes, int n_in,
                              void* d_out, int out_size, void* d_ws, size_t ws_size,
                              hipStream_t stream) {
    const int*   edges      = (const int*)  d_in[0];
    const float* nodes      = (const float*)d_in[1];
    const float* vels       = (const float*)d_in[2];
    const float* poses      = (const float*)d_in[3];
    const float* imu_drots  = (const float*)d_in[4];
    const float* imu_dtrans = (const float*)d_in[5];
    const float* imu_dvels  = (const float*)d_in[6];
    const float* dts        = (const float*)d_in[7];
    float* out = (float*)d_out;

    const int E = in_sizes[0] / 2;
    const int M = in_sizes[7];          // dts has M elements

    const size_t off_adjvel   = 6*(size_t)E;
    const size_t off_imurot   = off_adjvel + 3*(size_t)M;
    const size_t off_transvel = off_imurot + 3*(size_t)M;

    const int BLK = 256;
    edge_kernel<<<(E + BLK - 1) / BLK, BLK, 0, stream>>>(edges, nodes, poses, out, E);
    node_kernel<<<(M + BLK - 1) / BLK, BLK, 0, stream>>>(nodes, vels, imu_drots, imu_dtrans,
                                                         imu_dvels, dts, out, M,
                                                         off_adjvel, off_imurot, off_transvel);
}